// Round 12
// baseline (14632.524 us; speedup 1.0000x reference)
//
#include <hip/hip_runtime.h>
#include <math.h>

#define Hn 1024
#define Gn 4096   // 4*H
#define Bn 64
#define Tn 512
#define Vn 128
#define NWG 196
#define NPH 515        // phases: H0 t=p, X1 t=p-1, H1 t=p-2, C t=p-3
#define HSLOTB 131072  // BYTES per h-fragment slot: 64ks x 2pl x 2mt x 64lane x 8e (i8)
#define NGRP 7
#define GRPSZ 28       // NGRP*GRPSZ == NWG

typedef float f32x16 __attribute__((ext_vector_type(16)));
typedef int i32x16 __attribute__((ext_vector_type(16)));
typedef unsigned long long u64;

#define MFMAI8(a, b, c) __builtin_amdgcn_mfma_i32_32x32x16_i8(a, b, c, 0, 0, 0)

// quantization constants: Hint = round(h*32256), |Hint| <= 32255
#define QSCALE 32256.0f
#define C1K (65536.0f / (QSCALE * QSCALE))   // coefficient for P1 (hi*hi), x col-scale
#define C23K (256.0f / (QSCALE * QSCALE))    // coefficient for P23 (cross), x col-scale

// ---------------- L3-coherent (agent-scope atomic) access — validated r6/r11 path ----------------
__device__ __forceinline__ float coh_loadf(const float* p) {
  return __hip_atomic_load(p, __ATOMIC_RELAXED, __HIP_MEMORY_SCOPE_AGENT);
}
__device__ __forceinline__ void coh_storef(float* p, float v) {
  __hip_atomic_store(p, v, __ATOMIC_RELAXED, __HIP_MEMORY_SCOPE_AGENT);
}
__device__ __forceinline__ void coh_storeus(unsigned short* p, unsigned short v) {
  __hip_atomic_store(p, v, __ATOMIC_RELAXED, __HIP_MEMORY_SCOPE_AGENT);
}
__device__ __forceinline__ u64 coh_loadq(const u64* p) {
  return __hip_atomic_load(p, __ATOMIC_RELAXED, __HIP_MEMORY_SCOPE_AGENT);
}

// ---------------- numeric helpers (validated r2-r11) ----------------
__device__ __forceinline__ float sigf(float x) {
  float e = exp2f(x * -1.442695040888963f);
  return __fdividef(1.f, 1.f + e);
}
__device__ __forceinline__ float tanh_(float x) {
  x = fminf(fmaxf(x, -15.f), 15.f);
  float e = exp2f(x * -2.885390081777926f);
  return __fdividef(1.f - e, 1.f + e);
}
__device__ __forceinline__ int clampq(int v) {
  return v > 32255 ? 32255 : (v < -32255 ? -32255 : v);
}

// ---------------- EW0 = embed @ Wx0 + b0 (V x G), fp32 (validated) ----------------
__global__ void ew0_kernel(const float* __restrict__ embed, const float* __restrict__ Wx0,
                           const float* __restrict__ bias, float* __restrict__ EW0) {
  int n = blockIdx.x * 256 + threadIdx.x;
  int vb = blockIdx.y * 8;
  float acc[8] = {0, 0, 0, 0, 0, 0, 0, 0};
  for (int k = 0; k < Hn; k++) {
    float w = Wx0[(size_t)k * Gn + n];
#pragma unroll
    for (int i = 0; i < 8; i++)
      acc[i] = fmaf(embed[(vb + i) * Hn + k], w, acc[i]);
  }
  float bb = bias[n];
#pragma unroll
  for (int i = 0; i < 8; i++)
    EW0[(size_t)(vb + i) * Gn + n] = acc[i] + bb;
}

// ---------------- grid barrier (validated r6/r11; tgt = p+1) ----------------
__device__ __forceinline__ void gridbar(unsigned* bar, int p, int b) {
  asm volatile("s_waitcnt vmcnt(0)" ::: "memory");
  __syncthreads();
  if (threadIdx.x == 0) {
    unsigned* gcnt = bar + (b / GRPSZ) * 32;
    unsigned* ccnt = bar + 256;
    unsigned* flag = bar + 288;
    const unsigned tgt = (unsigned)(p + 1);
    unsigned old = __hip_atomic_fetch_add(gcnt, 1u, __ATOMIC_RELAXED, __HIP_MEMORY_SCOPE_AGENT);
    bool released = false;
    if (old == (unsigned)GRPSZ * tgt - 1u) {
      unsigned c = __hip_atomic_fetch_add(ccnt, 1u, __ATOMIC_RELAXED, __HIP_MEMORY_SCOPE_AGENT);
      if (c == (unsigned)NGRP * tgt - 1u) {
        __hip_atomic_store(flag, tgt, __ATOMIC_RELAXED, __HIP_MEMORY_SCOPE_AGENT);
        released = true;
      }
    }
    if (!released) {
      while (__hip_atomic_load(flag, __ATOMIC_RELAXED, __HIP_MEMORY_SCOPE_AGENT) < tgt)
        __builtin_amdgcn_s_sleep(2);
    }
  }
  __syncthreads();
}

// ---------------- persistent phase-pipelined kernel (r11 structure, fast tail) ----------------
// blocks: [0,64) H0, [64,128) X1, [128,192) H1, [192,196) C.
// LDS: bqhi 64KB | bqlo 64KB | xg 17408B (gates [64][65]) | cb 4096B
__global__ __launch_bounds__(512, 1)
void persist_kernel(const int* __restrict__ idx,
                    const float* __restrict__ Wx, const float* __restrict__ Wh,
                    const float* __restrict__ bias, const float* __restrict__ Wout,
                    const float* __restrict__ EW0,
                    unsigned char* __restrict__ h0f, unsigned char* __restrict__ h1f,
                    float* __restrict__ P, float* __restrict__ out,
                    unsigned* __restrict__ bar) {
  extern __shared__ char smem[];
  unsigned char* bqhi = (unsigned char*)smem;            // 65536 B: [nt2][64ks][lane][8e] i8
  unsigned char* bqlo = (unsigned char*)(smem + 65536);  // 65536 B
  float* xg = (float*)(smem + 131072);                   // 17408 B
  float* cb = (float*)(smem + 131072 + 17408);           // 4096 B

  const int b = blockIdx.x, tid = threadIdx.x;
  const int wv = tid >> 6, l = tid & 63;
  const int type = (b < 64) ? 0 : (b < 128) ? 1 : (b < 192) ? 2 : 3;
  const int i = b - ((type == 0) ? 0 : (type == 1) ? 64 : (type == 2) ? 128 : 192);
  const int mtv = wv & 1, khv = wv >> 1;                 // khv in [0,4), 16 ks each
  const int c32 = l & 31, o8 = (l >> 5) * 8;

  const float* Wsrc = (type == 0) ? Wh
                    : (type == 1) ? (Wx + (size_t)Hn * Gn)
                    : (type == 2) ? (Wh + (size_t)Hn * Gn) : Wout;

  // ---- pack pass 1: per-column absmax -> scales (validated r11) ----
  {
    float pmax0 = 0.f, pmax1 = 0.f;
    if (type < 3) {
      for (int nt = 0; nt < 2; nt++) {
        int colv = (c32 >> 3) * Hn + 16 * i + nt * 8 + (c32 & 7);
        float pm = 0.f;
        for (int kk = 0; kk < 8; kk++) {
          int ks = wv * 8 + kk;
#pragma unroll
          for (int e = 0; e < 8; e++)
            pm = fmaxf(pm, fabsf(Wsrc[(size_t)(ks * 16 + o8 + e) * Gn + colv]));
        }
        if (nt) pmax1 = pm; else pmax0 = pm;
      }
    } else {
      int colv = 32 * i + c32;
      for (int kk = 0; kk < 8; kk++) {
        int ks = wv * 8 + kk;
#pragma unroll
        for (int e = 0; e < 8; e++)
          pmax0 = fmaxf(pmax0, fabsf(Wout[(size_t)(ks * 16 + o8 + e) * Vn + colv]));
      }
      pmax1 = 1.f;
    }
    int g = wv * 2 + (l >> 5);
    xg[g * 64 + c32] = pmax0;
    xg[g * 64 + 32 + c32] = pmax1;
  }
  __syncthreads();
  if (tid < 64) {
    float s = 1e-20f;
    for (int g = 0; g < 16; g++) s = fmaxf(s, xg[g * 64 + tid]);
    xg[1024 + tid] = s;
  }
  __syncthreads();
  const float sc0 = xg[1024 + c32], sc1 = xg[1024 + 32 + c32];
  const float qs0 = QSCALE / sc0, qs1 = QSCALE / sc1;
  const float c1v0 = sc0 * C1K, c1v1 = sc1 * C1K;
  const float c23v0 = sc0 * C23K, c23v1 = sc1 * C23K;
  __syncthreads();

  // ---- pack pass 2: quantize weights into LDS i8 planes (validated r11) ----
  {
    const int ntN = (type < 3) ? 2 : 1;
    for (int nt = 0; nt < ntN; nt++) {
      int colv; size_t stride;
      if (type < 3) { colv = (c32 >> 3) * Hn + 16 * i + nt * 8 + (c32 & 7); stride = Gn; }
      else { colv = 32 * i + c32; stride = Vn; }
      float qs = nt ? qs1 : qs0;
      for (int kk = 0; kk < 8; kk++) {
        int ks = wv * 8 + kk;
        u64 hq = 0, lq = 0;
#pragma unroll
        for (int e = 0; e < 8; e++) {
          float w = Wsrc[(size_t)(ks * 16 + o8 + e) * stride + colv];
          int Wi = clampq((int)rintf(w * qs));
          int bh = (Wi + 128) >> 8;
          int bl = Wi - (bh << 8);
          hq |= (u64)(unsigned char)(bh & 0xFF) << (8 * e);
          lq |= (u64)(unsigned char)(bl & 0xFF) << (8 * e);
        }
        size_t off = ((size_t)nt * 64 + ks) * 512 + (size_t)l * 8;
        *(u64*)(bqhi + off) = hq;
        *(u64*)(bqlo + off) = lq;
      }
    }
  }
  for (int q = tid; q < 1024; q += 512) cb[q] = 0.f;

  // ---- hoisted loop-invariant bias (type 2 update) ----
  const int jl0 = (tid >> 6) << 1;        // update mapping: 2 cells/thread
  const int ur = tid & 63;
  const int ntc = jl0 >> 3;
  float bb2[8];
  if (type == 2) {
#pragma unroll
    for (int q = 0; q < 2; ++q) {
      int j = 16 * i + jl0 + q;
#pragma unroll
      for (int g = 0; g < 4; ++g) bb2[q * 4 + g] = bias[Gn + g * Hn + j];
    }
  }
  __syncthreads();

  // ---- phase loop ----
  for (int p = 0; p < NPH; ++p) {
    const int sA = (p + 1) & 1;
    int t; bool active;
    if (type == 0)      { t = p;     active = (t < Tn); }
    else if (type == 1) { t = p - 1; active = (t >= 0 && t < Tn); }
    else if (type == 2) { t = p - 2; active = (t >= 0 && t < Tn); }
    else                { t = p - 3; active = (t >= 0 && t < Tn); }

    if (active) {
      // ---- prefetch update operands EARLY (hide under A transport) ----
      float pre[8];
      if (type == 0) {
        const int v = idx[ur * Tn + t];
        const float* er = EW0 + (size_t)v * Gn + 16 * i + jl0;
#pragma unroll
        for (int q = 0; q < 2; ++q)
#pragma unroll
          for (int g = 0; g < 4; ++g)
            pre[q * 4 + g] = coh_loadf(er + q + g * Hn);
      } else if (type == 2) {
        const float* pr = P + ((size_t)(t & 1) * 64 + i) * 4096 + ur * 64 + ntc * 32;
#pragma unroll
        for (int q = 0; q < 2; ++q)
#pragma unroll
          for (int g = 0; g < 4; ++g)
            pre[q * 4 + g] = coh_loadf(pr + g * 8 + ((jl0 & 7) + q));
      }

      const unsigned char* A = ((type <= 1) ? h0f : h1f) + (size_t)sA * HSLOTB;
      i32x16 p1a = {}, p23a = {}, p1b = {}, p23b = {};
      const int ks0 = khv * 16;
#pragma unroll
      for (int k2 = 0; k2 < 16; ++k2) {
        const int ks = ks0 + k2;
        long ahi = (long)coh_loadq((const u64*)(A + ((size_t)ks * 4 + mtv) * 512 + (size_t)l * 8));
        long alo = (long)coh_loadq((const u64*)(A + ((size_t)ks * 4 + 2 + mtv) * 512 + (size_t)l * 8));
        size_t bo = (size_t)ks * 512 + (size_t)l * 8;
        long bh0 = *(const long*)(bqhi + bo);
        long bl0 = *(const long*)(bqlo + bo);
        p1a = MFMAI8(ahi, bh0, p1a);
        p23a = MFMAI8(ahi, bl0, p23a);
        p23a = MFMAI8(alo, bh0, p23a);
        if (type < 3) {
          long bh1 = *(const long*)(bqhi + bo + 32768);
          long bl1 = *(const long*)(bqlo + bo + 32768);
          p1b = MFMAI8(ahi, bh1, p1b);
          p23b = MFMAI8(ahi, bl1, p23b);
          p23b = MFMAI8(alo, bh1, p23b);
        }
      }
      // int partials -> fp32 gate units (exact: |P| < 2^24)
      f32x16 acc0, acc1;
#pragma unroll
      for (int r = 0; r < 16; ++r) {
        acc0[r] = c1v0 * (float)p1a[r] + c23v0 * (float)p23a[r];
        acc1[r] = (type < 3) ? (c1v1 * (float)p1b[r] + c23v1 * (float)p23b[r]) : 0.f;
      }

      // ---- single-round reduce: khv0 stores, khv1-3 LDS-float-atomic add ----
      if (khv == 0) {
#pragma unroll
        for (int r = 0; r < 16; ++r) {
          int row = (r & 3) + 8 * (r >> 2) + 4 * (l >> 5) + 32 * mtv;
          xg[row * 65 + c32] = acc0[r];
          xg[row * 65 + 32 + c32] = acc1[r];
        }
      }
      __syncthreads();
      if (khv != 0) {
#pragma unroll
        for (int r = 0; r < 16; ++r) {
          int row = (r & 3) + 8 * (r >> 2) + 4 * (l >> 5) + 32 * mtv;
          atomicAdd(&xg[row * 65 + c32], acc0[r]);
          atomicAdd(&xg[row * 65 + 32 + c32], acc1[r]);
        }
      }
      __syncthreads();

      if (type == 1) {
        // ---- writeback P: coalesced copy xg -> P (all 512 threads) ----
        float* pp = P + ((size_t)(t & 1) * 64 + i) * 4096;
#pragma unroll
        for (int k = 0; k < 8; ++k) {
          int r = wv * 8 + k;
          coh_storef(pp + r * 64 + l, xg[r * 65 + l]);
        }
      } else if (type == 3) {
        // ---- writeback out: coalesced copy (half-wave rows) ----
        const int oc = tid & 31, org = tid >> 5;   // 16 row-groups x 4 rows
#pragma unroll
        for (int k = 0; k < 4; ++k) {
          int r = org * 4 + k;
          coh_storef(out + ((size_t)r * Tn + t) * Vn + 32 * i + oc, xg[r * 65 + oc]);
        }
      } else {
        // ---- LSTM update: 512 threads x 2 cells, prefetched operands ----
        unsigned char* dst = ((type == 0) ? h0f : h1f) + (size_t)(p & 1) * HSLOTB;
        unsigned hi2 = 0, lo2 = 0;
#pragma unroll
        for (int q = 0; q < 2; ++q) {
          int jl = jl0 + q;
          int jo = jl & 7;
          float gi_ = xg[ur * 65 + ntc * 32 + jo] + pre[q * 4 + 0];
          float gf_ = xg[ur * 65 + ntc * 32 + 8 + jo] + pre[q * 4 + 1];
          float gg_ = xg[ur * 65 + ntc * 32 + 16 + jo] + pre[q * 4 + 2];
          float go_ = xg[ur * 65 + ntc * 32 + 24 + jo] + pre[q * 4 + 3];
          if (type == 2) {
            gi_ += bb2[q * 4 + 0]; gf_ += bb2[q * 4 + 1];
            gg_ += bb2[q * 4 + 2]; go_ += bb2[q * 4 + 3];
          }
          float c_ = cb[jl * 64 + ur];
          float cn = sigf(gf_) * c_ + sigf(gi_) * tanh_(gg_);
          float hn = sigf(go_) * tanh_(cn);
          cb[jl * 64 + ur] = cn;
          int Hq = clampq((int)rintf(hn * QSCALE));
          int ah8 = (Hq + 128) >> 8;
          int al8 = Hq - (ah8 << 8);
          hi2 |= ((unsigned)(unsigned char)(ah8 & 0xFF)) << (8 * q);
          lo2 |= ((unsigned)(unsigned char)(al8 & 0xFF)) << (8 * q);
        }
        const int lt = (ur & 31) | ((jl0 >> 3) << 5);
        const int e0 = jl0 & 7;               // 0,2,4,6 -> 2B aligned
        const int mtt = ur >> 5;
        size_t offh = ((size_t)i * 4 + mtt) * 512 + (size_t)lt * 8 + e0;
        coh_storeus((unsigned short*)(dst + offh), (unsigned short)hi2);
        coh_storeus((unsigned short*)(dst + offh + 1024), (unsigned short)lo2);
      }
    }
    gridbar(bar, p, b);
  }
}

// =======================================================================
extern "C" void kernel_launch(void* const* d_in, const int* in_sizes, int n_in,
                              void* d_out, int out_size, void* d_ws, size_t ws_size,
                              hipStream_t stream) {
  const int* idx = (const int*)d_in[0];        // (B,T) int32
  const float* embed = (const float*)d_in[1];  // (V,H)
  const float* Wx = (const float*)d_in[2];     // (L,H,4H)
  const float* Wh = (const float*)d_in[3];     // (L,H,4H)
  const float* bias = (const float*)d_in[4];   // (L,4H)
  const float* Wout = (const float*)d_in[5];   // (H,V)
  float* out = (float*)d_out;                  // (B,T,V) fp32

  // workspace: EW0 2MB | h0f 256KB | h1f 256KB | P 2MB | bar 4KB
  float* EW0 = (float*)d_ws;                               // 524288 f
  unsigned char* h0f = (unsigned char*)(EW0 + 524288);     // 2 x HSLOTB bytes
  unsigned char* h1f = h0f + 2 * HSLOTB;
  float* P = (float*)(h1f + 2 * HSLOTB);                   // 2 x 64 x 4096 f
  unsigned* bar = (unsigned*)(P + 524288);

  hipMemsetAsync(h0f, 0, (size_t)4 * HSLOTB, stream);      // h0f + h1f (zero state)
  hipMemsetAsync(bar, 0, 4096, stream);                    // barrier state (every call)

  ew0_kernel<<<dim3(Gn / 256, Vn / 8), 256, 0, stream>>>(embed, Wx, bias, EW0);

  hipFuncSetAttribute((const void*)persist_kernel,
                      hipFuncAttributeMaxDynamicSharedMemorySize, 152576);

  void* args[] = {(void*)&idx, (void*)&Wx, (void*)&Wh, (void*)&bias, (void*)&Wout,
                  (void*)&EW0, (void*)&h0f, (void*)&h1f,
                  (void*)&P, (void*)&out, (void*)&bar};
  hipLaunchCooperativeKernel((const void*)persist_kernel, dim3(NWG), dim3(512),
                             args, 152576, stream);

  (void)embed; (void)in_sizes; (void)n_in; (void)out_size; (void)ws_size;
}

// Round 13
// 6572.552 us; speedup vs baseline: 2.2263x; 2.2263x over previous
//
#include <hip/hip_runtime.h>
#include <math.h>

#define Hn 1024
#define Gn 4096   // 4*H
#define Bn 64
#define Tn 512
#define Vn 128
#define NWG 196
#define NPH 515        // phases: H0 t=p, X1 t=p-1, H1 t=p-2, C t=p-3
#define HSLOTB 131072  // BYTES per h-fragment slot: 64ks x 2pl x 2mt x 64lane x 8e (i8)
#define NGRP 7
#define GRPSZ 28       // NGRP*GRPSZ == NWG

typedef float f32x16 __attribute__((ext_vector_type(16)));
typedef int i32x16 __attribute__((ext_vector_type(16)));
typedef unsigned long long u64;

#define MFMAI8(a, b, c) __builtin_amdgcn_mfma_i32_32x32x16_i8(a, b, c, 0, 0, 0)

// quantization constants: Hint = round(h*32256), |Hint| <= 32255
#define QSCALE 32256.0f
#define C1K (65536.0f / (QSCALE * QSCALE))   // coefficient for P1 (hi*hi), x col-scale
#define C23K (256.0f / (QSCALE * QSCALE))    // coefficient for P23 (cross), x col-scale

// ---------------- L3-coherent (agent-scope atomic) access — validated r6/r11 path ----------------
__device__ __forceinline__ float coh_loadf(const float* p) {
  return __hip_atomic_load(p, __ATOMIC_RELAXED, __HIP_MEMORY_SCOPE_AGENT);
}
__device__ __forceinline__ void coh_storef(float* p, float v) {
  __hip_atomic_store(p, v, __ATOMIC_RELAXED, __HIP_MEMORY_SCOPE_AGENT);
}
__device__ __forceinline__ void coh_storeu(unsigned* p, unsigned v) {
  __hip_atomic_store(p, v, __ATOMIC_RELAXED, __HIP_MEMORY_SCOPE_AGENT);
}
__device__ __forceinline__ u64 coh_loadq(const u64* p) {
  return __hip_atomic_load(p, __ATOMIC_RELAXED, __HIP_MEMORY_SCOPE_AGENT);
}

// ---------------- numeric helpers (validated r2-r11) ----------------
__device__ __forceinline__ float sigf(float x) {
  float e = exp2f(x * -1.442695040888963f);
  return __fdividef(1.f, 1.f + e);
}
__device__ __forceinline__ float tanh_(float x) {
  x = fminf(fmaxf(x, -15.f), 15.f);
  float e = exp2f(x * -2.885390081777926f);
  return __fdividef(1.f - e, 1.f + e);
}
__device__ __forceinline__ int clampq(int v) {
  return v > 32255 ? 32255 : (v < -32255 ? -32255 : v);
}

// ---------------- EW0 = embed @ Wx0 + b0 (V x G), fp32 (validated) ----------------
__global__ void ew0_kernel(const float* __restrict__ embed, const float* __restrict__ Wx0,
                           const float* __restrict__ bias, float* __restrict__ EW0) {
  int n = blockIdx.x * 256 + threadIdx.x;
  int vb = blockIdx.y * 8;
  float acc[8] = {0, 0, 0, 0, 0, 0, 0, 0};
  for (int k = 0; k < Hn; k++) {
    float w = Wx0[(size_t)k * Gn + n];
#pragma unroll
    for (int i = 0; i < 8; i++)
      acc[i] = fmaf(embed[(vb + i) * Hn + k], w, acc[i]);
  }
  float bb = bias[n];
#pragma unroll
  for (int i = 0; i < 8; i++)
    EW0[(size_t)(vb + i) * Gn + n] = acc[i] + bb;
}

// ---------------- grid barrier (validated r6/r11; tgt = p+1) ----------------
__device__ __forceinline__ void gridbar(unsigned* bar, int p, int b) {
  asm volatile("s_waitcnt vmcnt(0)" ::: "memory");
  __syncthreads();
  if (threadIdx.x == 0) {
    unsigned* gcnt = bar + (b / GRPSZ) * 32;
    unsigned* ccnt = bar + 256;
    unsigned* flag = bar + 288;
    const unsigned tgt = (unsigned)(p + 1);
    unsigned old = __hip_atomic_fetch_add(gcnt, 1u, __ATOMIC_RELAXED, __HIP_MEMORY_SCOPE_AGENT);
    bool released = false;
    if (old == (unsigned)GRPSZ * tgt - 1u) {
      unsigned c = __hip_atomic_fetch_add(ccnt, 1u, __ATOMIC_RELAXED, __HIP_MEMORY_SCOPE_AGENT);
      if (c == (unsigned)NGRP * tgt - 1u) {
        __hip_atomic_store(flag, tgt, __ATOMIC_RELAXED, __HIP_MEMORY_SCOPE_AGENT);
        released = true;
      }
    }
    if (!released) {
      while (__hip_atomic_load(flag, __ATOMIC_RELAXED, __HIP_MEMORY_SCOPE_AGENT) < tgt)
        __builtin_amdgcn_s_sleep(2);
    }
  }
  __syncthreads();
}

// ---------------- persistent phase-pipelined kernel (r11 structure + prefetch) ----------------
// blocks: [0,64) H0, [64,128) X1, [128,192) H1, [192,196) C.
// LDS: bqhi 64KB | bqlo 64KB | xg 17408B | cb 4096B  (total 152576)
__global__ __launch_bounds__(512, 1)
void persist_kernel(const int* __restrict__ idx,
                    const float* __restrict__ Wx, const float* __restrict__ Wh,
                    const float* __restrict__ bias, const float* __restrict__ Wout,
                    const float* __restrict__ EW0,
                    unsigned char* __restrict__ h0f, unsigned char* __restrict__ h1f,
                    float* __restrict__ P, float* __restrict__ out,
                    unsigned* __restrict__ bar) {
  extern __shared__ char smem[];
  unsigned char* bqhi = (unsigned char*)smem;            // 65536 B: [nt2][64ks][lane][8e] i8
  unsigned char* bqlo = (unsigned char*)(smem + 65536);  // 65536 B
  float* xg = (float*)(smem + 131072);                   // 17408 B
  float* cb = (float*)(smem + 131072 + 17408);           // 4096 B

  const int b = blockIdx.x, tid = threadIdx.x;
  const int wv = tid >> 6, l = tid & 63;
  const int type = (b < 64) ? 0 : (b < 128) ? 1 : (b < 192) ? 2 : 3;
  const int i = b - ((type == 0) ? 0 : (type == 1) ? 64 : (type == 2) ? 128 : 192);
  const int mtv = wv & 1, khv = wv >> 1;                 // khv in [0,4), 16 ks each
  const int c32 = l & 31, o8 = (l >> 5) * 8;

  const float* Wsrc = (type == 0) ? Wh
                    : (type == 1) ? (Wx + (size_t)Hn * Gn)
                    : (type == 2) ? (Wh + (size_t)Hn * Gn) : Wout;

  // ---- pack pass 1: per-column absmax -> scales (validated r11) ----
  {
    float pmax0 = 0.f, pmax1 = 0.f;
    if (type < 3) {
      for (int nt = 0; nt < 2; nt++) {
        int colv = (c32 >> 3) * Hn + 16 * i + nt * 8 + (c32 & 7);
        float pm = 0.f;
        for (int kk = 0; kk < 8; kk++) {
          int ks = wv * 8 + kk;
#pragma unroll
          for (int e = 0; e < 8; e++)
            pm = fmaxf(pm, fabsf(Wsrc[(size_t)(ks * 16 + o8 + e) * Gn + colv]));
        }
        if (nt) pmax1 = pm; else pmax0 = pm;
      }
    } else {
      int colv = 32 * i + c32;
      for (int kk = 0; kk < 8; kk++) {
        int ks = wv * 8 + kk;
#pragma unroll
        for (int e = 0; e < 8; e++)
          pmax0 = fmaxf(pmax0, fabsf(Wout[(size_t)(ks * 16 + o8 + e) * Vn + colv]));
      }
      pmax1 = 1.f;
    }
    int g = wv * 2 + (l >> 5);
    xg[g * 64 + c32] = pmax0;
    xg[g * 64 + 32 + c32] = pmax1;
  }
  __syncthreads();
  if (tid < 64) {
    float s = 1e-20f;
    for (int g = 0; g < 16; g++) s = fmaxf(s, xg[g * 64 + tid]);
    xg[1024 + tid] = s;
  }
  __syncthreads();
  const float sc0 = xg[1024 + c32], sc1 = xg[1024 + 32 + c32];
  const float qs0 = QSCALE / sc0, qs1 = QSCALE / sc1;
  const float c1v0 = sc0 * C1K, c1v1 = sc1 * C1K;
  const float c23v0 = sc0 * C23K, c23v1 = sc1 * C23K;
  __syncthreads();

  // ---- pack pass 2: quantize weights into LDS i8 planes (validated r11) ----
  {
    const int ntN = (type < 3) ? 2 : 1;
    for (int nt = 0; nt < ntN; nt++) {
      int colv; size_t stride;
      if (type < 3) { colv = (c32 >> 3) * Hn + 16 * i + nt * 8 + (c32 & 7); stride = Gn; }
      else { colv = 32 * i + c32; stride = Vn; }
      float qs = nt ? qs1 : qs0;
      for (int kk = 0; kk < 8; kk++) {
        int ks = wv * 8 + kk;
        u64 hq = 0, lq = 0;
#pragma unroll
        for (int e = 0; e < 8; e++) {
          float w = Wsrc[(size_t)(ks * 16 + o8 + e) * stride + colv];
          int Wi = clampq((int)rintf(w * qs));
          int bh = (Wi + 128) >> 8;
          int bl = Wi - (bh << 8);
          hq |= (u64)(unsigned char)(bh & 0xFF) << (8 * e);
          lq |= (u64)(unsigned char)(bl & 0xFF) << (8 * e);
        }
        size_t off = ((size_t)nt * 64 + ks) * 512 + (size_t)l * 8;
        *(u64*)(bqhi + off) = hq;
        *(u64*)(bqlo + off) = lq;
      }
    }
  }
  for (int q = tid; q < 1024; q += 512) cb[q] = 0.f;

  // ---- hoisted loop-invariant bias for type-2 update threads (tid<256) ----
  const int ujl0 = (tid >> 6) << 2;   // 0,4,8,12 (meaningful for tid<256)
  const int ur = tid & 63;
  const int untc = ujl0 >> 3;
  float bb4[16];
  if (type == 2 && tid < 256) {
#pragma unroll
    for (int q = 0; q < 4; ++q) {
      int j = 16 * i + ujl0 + q;
#pragma unroll
      for (int g = 0; g < 4; ++g) bb4[q * 4 + g] = bias[Gn + g * Hn + j];
    }
  }
  __syncthreads();

  // ---- phase loop ----
  for (int p = 0; p < NPH; ++p) {
    const int sA = (p + 1) & 1;
    int t; bool active;
    if (type == 0)      { t = p;     active = (t < Tn); }
    else if (type == 1) { t = p - 1; active = (t >= 0 && t < Tn); }
    else if (type == 2) { t = p - 2; active = (t >= 0 && t < Tn); }
    else                { t = p - 3; active = (t >= 0 && t < Tn); }

    if (active) {
      // ---- prefetch update gathers EARLY (hide latency under A transport) ----
      float pre[16];
      if (type == 0 && tid < 256) {
        const int v = idx[ur * Tn + t];
        const float* er = EW0 + (size_t)v * Gn + 16 * i + ujl0;
#pragma unroll
        for (int q = 0; q < 4; ++q)
#pragma unroll
          for (int g = 0; g < 4; ++g)
            pre[q * 4 + g] = coh_loadf(er + q + g * Hn);
      } else if (type == 2 && tid < 256) {
        const float* pr = P + ((size_t)(t & 1) * 64 + i) * 4096 + ur * 64 + untc * 32;
#pragma unroll
        for (int q = 0; q < 4; ++q)
#pragma unroll
          for (int g = 0; g < 4; ++g)
            pre[q * 4 + g] = coh_loadf(pr + g * 8 + ((ujl0 & 7) + q));
      }

      const unsigned char* A = ((type <= 1) ? h0f : h1f) + (size_t)sA * HSLOTB;
      i32x16 p1a = {}, p23a = {}, p1b = {}, p23b = {};
      const int ks0 = khv * 16;
#pragma unroll
      for (int k2 = 0; k2 < 16; ++k2) {
        const int ks = ks0 + k2;
        long ahi = (long)coh_loadq((const u64*)(A + ((size_t)ks * 4 + mtv) * 512 + (size_t)l * 8));
        long alo = (long)coh_loadq((const u64*)(A + ((size_t)ks * 4 + 2 + mtv) * 512 + (size_t)l * 8));
        size_t bo = (size_t)ks * 512 + (size_t)l * 8;
        long bh0 = *(const long*)(bqhi + bo);
        long bl0 = *(const long*)(bqlo + bo);
        p1a = MFMAI8(ahi, bh0, p1a);
        p23a = MFMAI8(ahi, bl0, p23a);
        p23a = MFMAI8(alo, bh0, p23a);
        if (type < 3) {
          long bh1 = *(const long*)(bqhi + bo + 32768);
          long bl1 = *(const long*)(bqlo + bo + 32768);
          p1b = MFMAI8(ahi, bh1, p1b);
          p23b = MFMAI8(ahi, bl1, p23b);
          p23b = MFMAI8(alo, bh1, p23b);
        }
      }
      // int partials -> fp32 gate units (exact: |P| < 2^24)
      f32x16 acc0, acc1;
#pragma unroll
      for (int r = 0; r < 16; ++r) {
        acc0[r] = c1v0 * (float)p1a[r] + c23v0 * (float)p23a[r];
        acc1[r] = (type < 3) ? (c1v1 * (float)p1b[r] + c23v1 * (float)p23b[r]) : 0.f;
      }

      // ---- 4-way kh reduce, conflict-free [tile][r][lane] layout (validated r11) ----
#pragma unroll
      for (int rd = 1; rd < 4; ++rd) {
        if (khv == rd) {
          float* s0 = xg + (mtv * 2 + 0) * 1024 + l;
          float* s1 = xg + (mtv * 2 + 1) * 1024 + l;
#pragma unroll
          for (int r = 0; r < 16; ++r) { s0[r * 64] = acc0[r]; s1[r * 64] = acc1[r]; }
        }
        __syncthreads();
        if (khv == 0) {
          const float* s0 = xg + (mtv * 2 + 0) * 1024 + l;
          const float* s1 = xg + (mtv * 2 + 1) * 1024 + l;
#pragma unroll
          for (int r = 0; r < 16; ++r) { acc0[r] += s0[r * 64]; acc1[r] += s1[r * 64]; }
        }
        __syncthreads();
      }

      if (type == 1) {
        if (khv == 0) {
          float* pp = P + ((size_t)(t & 1) * 64 + i) * 4096;
#pragma unroll
          for (int r = 0; r < 16; ++r) {
            int row = (r & 3) + 8 * (r >> 2) + 4 * (l >> 5) + 32 * mtv;
            coh_storef(pp + row * 64 + (l & 31), acc0[r]);
            coh_storef(pp + row * 64 + 32 + (l & 31), acc1[r]);
          }
        }
      } else if (type == 3) {
        if (khv == 0) {
#pragma unroll
          for (int r = 0; r < 16; ++r) {
            int row = (r & 3) + 8 * (r >> 2) + 4 * (l >> 5) + 32 * mtv;
            coh_storef(out + ((size_t)row * Tn + t) * Vn + 32 * i + (l & 31), acc0[r]);
          }
        }
      } else {
        // ---- type 0/2: gates -> LDS (stride 65), LSTM update (r11-exact, pre[] operands) ----
        if (khv == 0) {
#pragma unroll
          for (int r = 0; r < 16; ++r) {
            int row = (r & 3) + 8 * (r >> 2) + 4 * (l >> 5) + 32 * mtv;
            xg[row * 65 + (l & 31)] = acc0[r];
            xg[row * 65 + 32 + (l & 31)] = acc1[r];
          }
        }
        __syncthreads();
        unsigned char* dst = ((type == 0) ? h0f : h1f) + (size_t)(p & 1) * HSLOTB;
        if (tid < 256) {
          unsigned hiw = 0, low = 0;
#pragma unroll
          for (int q = 0; q < 4; ++q) {
            int jl = ujl0 + q;
            int jo = jl & 7;
            float gi_ = xg[ur * 65 + untc * 32 + jo];
            float gf_ = xg[ur * 65 + untc * 32 + 8 + jo];
            float gg_ = xg[ur * 65 + untc * 32 + 16 + jo];
            float go_ = xg[ur * 65 + untc * 32 + 24 + jo];
            if (type == 0) {
              gi_ += pre[q * 4 + 0];
              gf_ += pre[q * 4 + 1];
              gg_ += pre[q * 4 + 2];
              go_ += pre[q * 4 + 3];
            } else {
              gi_ += pre[q * 4 + 0] + bb4[q * 4 + 0];
              gf_ += pre[q * 4 + 1] + bb4[q * 4 + 1];
              gg_ += pre[q * 4 + 2] + bb4[q * 4 + 2];
              go_ += pre[q * 4 + 3] + bb4[q * 4 + 3];
            }
            float c_ = cb[jl * 64 + ur];
            float cn = sigf(gf_) * c_ + sigf(gi_) * tanh_(gg_);
            float hn = sigf(go_) * tanh_(cn);
            cb[jl * 64 + ur] = cn;
            int Hq = clampq((int)rintf(hn * QSCALE));
            int ah8 = (Hq + 128) >> 8;
            int al8 = Hq - (ah8 << 8);
            hiw |= ((unsigned)(unsigned char)(ah8 & 0xFF)) << (8 * q);
            low |= ((unsigned)(unsigned char)(al8 & 0xFF)) << (8 * q);
          }
          const int lt = (ur & 31) | ((ujl0 >> 3) << 5);
          const int e0 = ujl0 & 7;               // 0 or 4 -> 4B aligned
          const int mtt = ur >> 5;
          size_t offh = ((size_t)i * 4 + mtt) * 512 + (size_t)lt * 8 + e0;
          coh_storeu((unsigned*)(dst + offh), hiw);
          coh_storeu((unsigned*)(dst + offh + 1024), low);
        }
      }
    }
    gridbar(bar, p, b);
  }
}

// =======================================================================
extern "C" void kernel_launch(void* const* d_in, const int* in_sizes, int n_in,
                              void* d_out, int out_size, void* d_ws, size_t ws_size,
                              hipStream_t stream) {
  const int* idx = (const int*)d_in[0];        // (B,T) int32
  const float* embed = (const float*)d_in[1];  // (V,H)
  const float* Wx = (const float*)d_in[2];     // (L,H,4H)
  const float* Wh = (const float*)d_in[3];     // (L,H,4H)
  const float* bias = (const float*)d_in[4];   // (L,4H)
  const float* Wout = (const float*)d_in[5];   // (H,V)
  float* out = (float*)d_out;                  // (B,T,V) fp32

  // workspace: EW0 2MB | h0f 256KB | h1f 256KB | P 2MB | bar 4KB
  float* EW0 = (float*)d_ws;                               // 524288 f
  unsigned char* h0f = (unsigned char*)(EW0 + 524288);     // 2 x HSLOTB bytes
  unsigned char* h1f = h0f + 2 * HSLOTB;
  float* P = (float*)(h1f + 2 * HSLOTB);                   // 2 x 64 x 4096 f
  unsigned* bar = (unsigned*)(P + 524288);

  hipMemsetAsync(h0f, 0, (size_t)4 * HSLOTB, stream);      // h0f + h1f (zero state)
  hipMemsetAsync(bar, 0, 4096, stream);                    // barrier state (every call)

  ew0_kernel<<<dim3(Gn / 256, Vn / 8), 256, 0, stream>>>(embed, Wx, bias, EW0);

  hipFuncSetAttribute((const void*)persist_kernel,
                      hipFuncAttributeMaxDynamicSharedMemorySize, 152576);

  void* args[] = {(void*)&idx, (void*)&Wx, (void*)&Wh, (void*)&bias, (void*)&Wout,
                  (void*)&EW0, (void*)&h0f, (void*)&h1f,
                  (void*)&P, (void*)&out, (void*)&bar};
  hipLaunchCooperativeKernel((const void*)persist_kernel, dim3(NWG), dim3(512),
                             args, 152576, stream);

  (void)embed; (void)in_sizes; (void)n_in; (void)out_size; (void)ws_size;
}